// Round 3
// baseline (449.377 us; speedup 1.0000x reference)
//
#include <hip/hip_runtime.h>
#include <cstdint>
#include <cstddef>

// ---------------------------------------------------------------------------
// LSTM cell + 3-layer decoder, MI355X (gfx950)
// B=8192, H=1024, D_IN=1024, D1=512, D2=341(pad 384), A=512
// R3: (a) XOR-swizzled LDS staging in gates GEMM (kills the 16.8e6 bank
// conflicts: fragment reads previously hit 2 bank-quads 8-way; swizzle
// chunk c -> row=c>>2, kq=(c&3)^((row>>1)&3) spreads quarter-waves 2-way).
// (b) Decoder fused into ONE kernel (3 GEMMs + softmax): 512 blocks x 512
// threads, 16 rows/block, d1/d2 in padded LDS, logits+softmax in registers.
// ---------------------------------------------------------------------------

typedef _Float16 half_t;
typedef _Float16 half8 __attribute__((ext_vector_type(8)));
typedef _Float16 half4v __attribute__((ext_vector_type(4)));
typedef float float4v __attribute__((ext_vector_type(4)));

#define GLD_LDS16(gptr, lptr)                                                  \
  __builtin_amdgcn_global_load_lds(                                            \
      (const __attribute__((address_space(1))) void*)(gptr),                   \
      (__attribute__((address_space(3))) void*)(lptr), 16, 0, 0)

__device__ __forceinline__ float fsig(float x) {
  return 1.0f / (1.0f + __expf(-x));
}
__device__ __forceinline__ float ftanh_(float x) {
  const float e = __expf(2.0f * x);
  return 1.0f - 2.0f / (e + 1.0f);
}

// ---------------------------------------------------------------------------
// Gates GEMM with fused LSTM epilogue, swizzled LDS staging.
// A=XH [8192,2048], Bw=WALL [4096,2048], bias=BALL[4096], c [8192,1024].
// Column n: gate g=(n>>4)&3 == j-fragment index; unit u=((n>>6)<<4)|(n&15).
// ---------------------------------------------------------------------------
__global__ __launch_bounds__(256) void gemm_gates(const half_t* __restrict__ A,
                                                  const half_t* __restrict__ Bw,
                                                  const float* __restrict__ bias,
                                                  const float* __restrict__ cin,
                                                  float* __restrict__ hout,
                                                  half_t* __restrict__ h2) {
  constexpr int K = 2048;
  __shared__ alignas(16) half_t As[128 * 32];
  __shared__ alignas(16) half_t Bs[128 * 32];
  const int tid = threadIdx.x;
  const int lane = tid & 63;
  const int wave = tid >> 6;
  const int m = lane & 15;
  const int q = lane >> 4;
  const int sx = (m >> 1) & 3;  // fragment-read swizzle term
  const size_t tile_m = (size_t)blockIdx.y * 128;
  const size_t tile_n = (size_t)blockIdx.x * 128;
  const int wm = (wave >> 1) * 64;
  const int wn = (wave & 1) * 64;

  // swizzled staging: chunk c -> row=c>>2, kq=(c&3)^((row>>1)&3)
  const int cA0 = tid, rA0 = cA0 >> 2, kA0 = ((cA0 & 3) ^ ((rA0 >> 1) & 3));
  const int cA1 = 256 + tid, rA1 = cA1 >> 2, kA1 = ((cA1 & 3) ^ ((rA1 >> 1) & 3));
  const half_t* Ag0 = A + (tile_m + rA0) * (size_t)K + kA0 * 8;
  const half_t* Ag1 = A + (tile_m + rA1) * (size_t)K + kA1 * 8;
  const half_t* Bg0 = Bw + (tile_n + rA0) * (size_t)K + kA0 * 8;
  const half_t* Bg1 = Bw + (tile_n + rA1) * (size_t)K + kA1 * 8;
  const int p0 = cA0 * 16, p1 = cA1 * 16;  // LDS byte offsets (lane-contiguous)

  float4v acc[4][4] = {};
  for (int k0 = 0; k0 < K; k0 += 32) {
    __syncthreads();
    GLD_LDS16(Ag0 + k0, (char*)As + p0);
    GLD_LDS16(Ag1 + k0, (char*)As + p1);
    GLD_LDS16(Bg0 + k0, (char*)Bs + p0);
    GLD_LDS16(Bg1 + k0, (char*)Bs + p1);
    __syncthreads();
    const int ks = (q ^ sx) * 8;  // swizzled k-quad position (halves)
    half8 af[4], bf[4];
#pragma unroll
    for (int i = 0; i < 4; ++i)
      af[i] = *(const half8*)(As + (wm + i * 16 + m) * 32 + ks);
#pragma unroll
    for (int j = 0; j < 4; ++j)
      bf[j] = *(const half8*)(Bs + (wn + j * 16 + m) * 32 + ks);
#pragma unroll
    for (int i = 0; i < 4; ++i)
#pragma unroll
      for (int j = 0; j < 4; ++j)
        acc[i][j] =
            __builtin_amdgcn_mfma_f32_16x16x32_f16(af[i], bf[j], acc[i][j], 0, 0, 0);
  }

  // fused LSTM epilogue (C/D layout: col=lane&15, row=quad*4+reg [m89])
  const int nwave = (int)tile_n + wn;                // multiple of 64
  const size_t u = (size_t)((nwave >> 6) << 4) + m;  // hidden unit index
  float bg[4];
#pragma unroll
  for (int g = 0; g < 4; ++g) bg[g] = bias[nwave + g * 16 + m];
#pragma unroll
  for (int i = 0; i < 4; ++i) {
#pragma unroll
    for (int r = 0; r < 4; ++r) {
      const size_t row = tile_m + wm + q * 4 + i * 16 + r;
      const size_t off = row * 1024 + u;
      const float F = fsig(acc[i][0][r] + bg[0]);
      const float I = fsig(acc[i][1][r] + bg[1]);
      const float S = ftanh_(acc[i][2][r] + bg[2]);
      const float O = fsig(acc[i][3][r] + bg[3]);
      const float cn = cin[off] * F + I * S;
      const float hn = O * ftanh_(cn);
      hout[off] = hn;
      h2[off] = (half_t)hn;
    }
  }
}

// ---------------------------------------------------------------------------
// Fused decoder: d1=tanh(H2@W1^T+b1); d2=tanh(d1@W2^T+b2); sm(d2@W3^T+b3).
// 512 blocks x 512 threads (8 waves), 16 rows/block. d1/d2 in padded LDS;
// B-tiles staged per BK=32 with the same XOR swizzle; logits in registers;
// softmax fused (quad-shuffle + cross-wave LDS reduce). LDS = 63.8 KB.
// ---------------------------------------------------------------------------
__global__ __launch_bounds__(512) void decoder_fused(
    const half_t* __restrict__ H2,  // [8192,1024]
    const half_t* __restrict__ W1,  // [512,1024]
    const float* __restrict__ b1,   // [512]
    const half_t* __restrict__ W2,  // [384,512] (rows 341.. zero)
    const float* __restrict__ b2,   // [384] (341.. zero)
    const half_t* __restrict__ W3,  // [512,384] (cols 341.. zero)
    const float* __restrict__ b3,   // [512]
    float* __restrict__ out) {      // [8192,512]
  __shared__ alignas(16) half_t Bs[512 * 32];    // 32 KB staging
  __shared__ alignas(16) half_t As[16 * 40];     // 1.25 KB (pad 8 halves)
  __shared__ alignas(16) half_t d1s[16 * 520];   // 16.25 KB (pad 8)
  __shared__ alignas(16) half_t d2s[16 * 392];   // 12.25 KB (pad 8)
  __shared__ float red[8 * 16];
  __shared__ float rowred[16];

  const int tid = threadIdx.x;
  const int lane = tid & 63;
  const int w = tid >> 6;  // 0..7
  const int m = lane & 15;
  const int q = lane >> 4;
  const int sx = (m >> 1) & 3;
  const size_t r0 = (size_t)blockIdx.x * 16;

  // ---- layer 1: d1[16][512] ----
  {
    float4v acc[4] = {};
    for (int kk = 0; kk < 1024; kk += 32) {
      __syncthreads();
#pragma unroll
      for (int p = 0; p < 4; ++p) {  // 512 rows x 4 chunks = 2048
        const int cch = p * 512 + tid;
        const int n = cch >> 2;
        const int kq = (cch & 3) ^ ((n >> 1) & 3);
        GLD_LDS16(W1 + (size_t)n * 1024 + kk + kq * 8, (char*)Bs + cch * 16);
      }
      if (tid < 64) {  // A-tile 16x32 = 1 KB, identity layout, padded rows
        const int row = tid >> 2;
        const int kq = tid & 3;
        const half8 v = *(const half8*)(H2 + (r0 + row) * 1024 + kk + kq * 8);
        *(half8*)(As + row * 40 + kq * 8) = v;
      }
      __syncthreads();
      const int ks = (q ^ sx) * 8;
      const half8 af = *(const half8*)(As + m * 40 + q * 8);
      half8 bf[4];
#pragma unroll
      for (int j = 0; j < 4; ++j)
        bf[j] = *(const half8*)(Bs + (w * 64 + j * 16 + m) * 32 + ks);
#pragma unroll
      for (int j = 0; j < 4; ++j)
        acc[j] = __builtin_amdgcn_mfma_f32_16x16x32_f16(af, bf[j], acc[j], 0, 0, 0);
    }
#pragma unroll
    for (int j = 0; j < 4; ++j) {
      const int col = w * 64 + j * 16 + m;
      const float bv = b1[col];
#pragma unroll
      for (int r = 0; r < 4; ++r)
        d1s[(q * 4 + r) * 520 + col] = (half_t)ftanh_(acc[j][r] + bv);
    }
  }

  // ---- layer 2: d2[16][384] ----
  {
    float4v acc[3] = {};
    for (int kk = 0; kk < 512; kk += 32) {
      __syncthreads();
#pragma unroll
      for (int p = 0; p < 3; ++p) {  // 384 rows x 4 chunks = 1536
        const int cch = p * 512 + tid;
        const int n = cch >> 2;
        const int kq = (cch & 3) ^ ((n >> 1) & 3);
        GLD_LDS16(W2 + (size_t)n * 512 + kk + kq * 8, (char*)Bs + cch * 16);
      }
      __syncthreads();
      const int ks = (q ^ sx) * 8;
      const half8 af = *(const half8*)(d1s + m * 520 + kk + q * 8);
      half8 bf[3];
#pragma unroll
      for (int j = 0; j < 3; ++j)
        bf[j] = *(const half8*)(Bs + (w * 48 + j * 16 + m) * 32 + ks);
#pragma unroll
      for (int j = 0; j < 3; ++j)
        acc[j] = __builtin_amdgcn_mfma_f32_16x16x32_f16(af, bf[j], acc[j], 0, 0, 0);
    }
#pragma unroll
    for (int j = 0; j < 3; ++j) {
      const int col = w * 48 + j * 16 + m;
      const float bv = b2[col];
#pragma unroll
      for (int r = 0; r < 4; ++r)
        d2s[(q * 4 + r) * 392 + col] = (half_t)ftanh_(acc[j][r] + bv);
    }
  }

  // ---- layer 3 + softmax ----
  {
    float4v acc[4] = {};
    for (int kk = 0; kk < 384; kk += 32) {
      __syncthreads();
#pragma unroll
      for (int p = 0; p < 4; ++p) {  // 512 rows x 4 chunks = 2048
        const int cch = p * 512 + tid;
        const int n = cch >> 2;
        const int kq = (cch & 3) ^ ((n >> 1) & 3);
        GLD_LDS16(W3 + (size_t)n * 384 + kk + kq * 8, (char*)Bs + cch * 16);
      }
      __syncthreads();
      const int ks = (q ^ sx) * 8;
      const half8 af = *(const half8*)(d2s + m * 392 + kk + q * 8);
      half8 bf[4];
#pragma unroll
      for (int j = 0; j < 4; ++j)
        bf[j] = *(const half8*)(Bs + (w * 64 + j * 16 + m) * 32 + ks);
#pragma unroll
      for (int j = 0; j < 4; ++j)
        acc[j] = __builtin_amdgcn_mfma_f32_16x16x32_f16(af, bf[j], acc[j], 0, 0, 0);
    }
    // logits: row = q*4+r, cols = w*64 + j*16 + m
    float lg[4][4];
#pragma unroll
    for (int j = 0; j < 4; ++j) {
      const float bv = b3[w * 64 + j * 16 + m];
#pragma unroll
      for (int r = 0; r < 4; ++r) lg[j][r] = acc[j][r] + bv;
    }
    // row max: in-lane over j, shuffle over m within quad, LDS across waves
    float pmax[4];
#pragma unroll
    for (int r = 0; r < 4; ++r) {
      float v = fmaxf(fmaxf(lg[0][r], lg[1][r]), fmaxf(lg[2][r], lg[3][r]));
#pragma unroll
      for (int d = 1; d < 16; d <<= 1) v = fmaxf(v, __shfl_xor(v, d, 64));
      pmax[r] = v;
    }
    if (m == 0) {
#pragma unroll
      for (int r = 0; r < 4; ++r) red[w * 16 + q * 4 + r] = pmax[r];
    }
    __syncthreads();
    if (tid < 16) {
      float v = red[tid];
#pragma unroll
      for (int ww = 1; ww < 8; ++ww) v = fmaxf(v, red[ww * 16 + tid]);
      rowred[tid] = v;
    }
    __syncthreads();
    float ex[4][4], psum[4];
#pragma unroll
    for (int r = 0; r < 4; ++r) {
      const float M = rowred[q * 4 + r];
      float s = 0.f;
#pragma unroll
      for (int j = 0; j < 4; ++j) {
        ex[j][r] = __expf(lg[j][r] - M);
        s += ex[j][r];
      }
#pragma unroll
      for (int d = 1; d < 16; d <<= 1) s += __shfl_xor(s, d, 64);
      psum[r] = s;
    }
    if (m == 0) {
#pragma unroll
      for (int r = 0; r < 4; ++r) red[w * 16 + q * 4 + r] = psum[r];
    }
    __syncthreads();
    if (tid < 16) {
      float s = 0.f;
#pragma unroll
      for (int ww = 0; ww < 8; ++ww) s += red[ww * 16 + tid];
      rowred[tid] = 1.0f / s;
    }
    __syncthreads();
#pragma unroll
    for (int r = 0; r < 4; ++r) {
      const int row = q * 4 + r;
      const float inv = rowred[row];
#pragma unroll
      for (int j = 0; j < 4; ++j)
        out[(r0 + row) * 512 + w * 64 + j * 16 + m] = ex[j][r] * inv;
    }
  }
}

// ---------------------------------------------------------------------------
// prep_pack: blocks [0,16384) -> XH f16 [8192,2048]; [16384,24576) -> WALL.
// WALL row n: g=(n>>4)&3, u=((n>>6)<<4)|(n&15); cols 0..1023=W_gi[u], rest=W_gh[u]
// ---------------------------------------------------------------------------
__global__ void prep_pack(const float* __restrict__ x, const float* __restrict__ h,
                          const float* __restrict__ Wfi, const float* __restrict__ Wfh,
                          const float* __restrict__ Wii, const float* __restrict__ Wih,
                          const float* __restrict__ Wsi, const float* __restrict__ Wsh,
                          const float* __restrict__ Woi, const float* __restrict__ Woh,
                          half_t* __restrict__ xh, half_t* __restrict__ wall) {
  const int bid = blockIdx.x;
  const float* src;
  half_t* dst;
  size_t idx;
  if (bid < 16384) {
    idx = ((size_t)bid * 256 + threadIdx.x) * 4;
    const size_t b = idx >> 11;
    const int col = (int)(idx & 2047);
    src = (col < 1024) ? (x + b * 1024 + col) : (h + b * 1024 + (col - 1024));
    dst = xh + idx;
  } else {
    idx = ((size_t)(bid - 16384) * 256 + threadIdx.x) * 4;
    const int n = (int)(idx >> 11);
    const int col = (int)(idx & 2047);
    const int g = (n >> 4) & 3;
    const size_t u = (size_t)(((n >> 6) << 4) | (n & 15));
    const float* Wi = (g == 0) ? Wfi : (g == 1) ? Wii : (g == 2) ? Wsi : Woi;
    const float* Wh = (g == 0) ? Wfh : (g == 1) ? Wih : (g == 2) ? Wsh : Woh;
    src = (col < 1024) ? (Wi + u * 1024 + col) : (Wh + u * 1024 + (col - 1024));
    dst = wall + idx;
  }
  const float4v v = *(const float4v*)src;
  half4v o;
  o.x = (half_t)v.x; o.y = (half_t)v.y; o.z = (half_t)v.z; o.w = (half_t)v.w;
  *(half4v*)dst = o;
}

// ---------------------------------------------------------------------------
// prep_small: WD1 [0,512) | WD2 [512,704) | WD3 [704,896) | BALL [896,912) |
//             BD2 [912,914)
// ---------------------------------------------------------------------------
__global__ void prep_small(const float* __restrict__ Wd1, const float* __restrict__ Wd2,
                           const float* __restrict__ Wd3, const float* __restrict__ bd2,
                           const float* __restrict__ bfi, const float* __restrict__ bfh,
                           const float* __restrict__ bii, const float* __restrict__ bih,
                           const float* __restrict__ bsi, const float* __restrict__ bsh,
                           const float* __restrict__ boi, const float* __restrict__ boh,
                           half_t* __restrict__ WD1, half_t* __restrict__ WD2h,
                           half_t* __restrict__ WD3h, float* __restrict__ BALL,
                           float* __restrict__ BD2) {
  const int bid = blockIdx.x;
  const int tid = threadIdx.x;
  if (bid < 512) {  // WD1: [512,1024] f32 -> f16
    const size_t i4 = ((size_t)bid * 256 + tid) * 4;
    const float4v v = *(const float4v*)(Wd1 + i4);
    half4v o;
    o.x = (half_t)v.x; o.y = (half_t)v.y; o.z = (half_t)v.z; o.w = (half_t)v.w;
    *(half4v*)(WD1 + i4) = o;
  } else if (bid < 704) {  // WD2: [341,512] -> [384,512], row-padded
    const size_t i4 = ((size_t)(bid - 512) * 256 + tid) * 4;
    const int r = (int)(i4 >> 9);
    const int cc = (int)(i4 & 511);
    half4v o;
    if (r < 341) {
      const float4v v = *(const float4v*)(Wd2 + (size_t)r * 512 + cc);
      o.x = (half_t)v.x; o.y = (half_t)v.y; o.z = (half_t)v.z; o.w = (half_t)v.w;
    } else {
      o.x = (half_t)0.f; o.y = (half_t)0.f; o.z = (half_t)0.f; o.w = (half_t)0.f;
    }
    *(half4v*)(WD2h + i4) = o;
  } else if (bid < 896) {  // WD3: [512,341] -> [512,384], col-padded
    const size_t i4 = ((size_t)(bid - 704) * 256 + tid) * 4;
    const int r = (int)(i4 / 384);
    const int cc = (int)(i4 - (size_t)r * 384);
    half4v o;
    o.x = (cc + 0 < 341) ? (half_t)Wd3[(size_t)r * 341 + cc + 0] : (half_t)0.f;
    o.y = (cc + 1 < 341) ? (half_t)Wd3[(size_t)r * 341 + cc + 1] : (half_t)0.f;
    o.z = (cc + 2 < 341) ? (half_t)Wd3[(size_t)r * 341 + cc + 2] : (half_t)0.f;
    o.w = (cc + 3 < 341) ? (half_t)Wd3[(size_t)r * 341 + cc + 3] : (half_t)0.f;
    *(half4v*)(WD3h + i4) = o;
  } else if (bid < 912) {  // BALL[4096], WALL row ordering
    const int n = (bid - 896) * 256 + tid;
    const int g = (n >> 4) & 3;
    const int u = ((n >> 6) << 4) | (n & 15);
    const float* bi = (g == 0) ? bfi : (g == 1) ? bii : (g == 2) ? bsi : boi;
    const float* bh = (g == 0) ? bfh : (g == 1) ? bih : (g == 2) ? bsh : boh;
    BALL[n] = bi[u] + bh[u];
  } else {  // BD2[384]
    const int i = (bid - 912) * 256 + tid;
    if (i < 384) BD2[i] = (i < 341) ? bd2[i] : 0.0f;
  }
}

// ---------------------------------------------------------------------------
extern "C" void kernel_launch(void* const* d_in, const int* in_sizes, int n_in,
                              void* d_out, int out_size, void* d_ws, size_t ws_size,
                              hipStream_t stream) {
  const float* x = (const float*)d_in[0];
  const float* h = (const float*)d_in[1];
  const float* c = (const float*)d_in[2];
  const float* Wfi = (const float*)d_in[3];  const float* bfi = (const float*)d_in[4];
  const float* Wfh = (const float*)d_in[5];  const float* bfh = (const float*)d_in[6];
  const float* Wii = (const float*)d_in[7];  const float* bii = (const float*)d_in[8];
  const float* Wih = (const float*)d_in[9];  const float* bih = (const float*)d_in[10];
  const float* Wsi = (const float*)d_in[11]; const float* bsi = (const float*)d_in[12];
  const float* Wsh = (const float*)d_in[13]; const float* bsh = (const float*)d_in[14];
  const float* Woi = (const float*)d_in[15]; const float* boi = (const float*)d_in[16];
  const float* Woh = (const float*)d_in[17]; const float* boh = (const float*)d_in[18];
  const float* Wd1 = (const float*)d_in[19]; const float* bd1 = (const float*)d_in[20];
  const float* Wd2 = (const float*)d_in[21]; const float* bd2 = (const float*)d_in[22];
  const float* Wd3 = (const float*)d_in[23]; const float* bd3 = (const float*)d_in[24];

  char* ws = (char*)d_ws;
  size_t o = 0;
  auto alloc = [&](size_t bytes) {
    size_t cur = o;
    o += (bytes + 255) & ~(size_t)255;
    return cur;
  };
  half_t* XH   = (half_t*)(ws + alloc((size_t)8192 * 2048 * 2));  // 33.5 MB
  half_t* WALL = (half_t*)(ws + alloc((size_t)4096 * 2048 * 2));  // 16.8 MB
  float*  BALL = (float*)(ws + alloc(4096 * 4));
  half_t* WD1  = (half_t*)(ws + alloc((size_t)512 * 1024 * 2));
  half_t* WD2  = (half_t*)(ws + alloc((size_t)384 * 512 * 2));
  float*  BD2  = (float*)(ws + alloc(384 * 4));
  half_t* WD3  = (half_t*)(ws + alloc((size_t)512 * 384 * 2));
  half_t* H2   = (half_t*)(ws + alloc((size_t)8192 * 1024 * 2));  // 16.8 MB

  float* h_out = (float*)d_out;                          // [8192,1024] f32
  float* d_outp = (float*)d_out + (size_t)8192 * 1024;   // [8192,512] f32

  // prep: 2 launches (inputs re-poisoned every call, so convert every call)
  prep_pack<<<24576, 256, 0, stream>>>(x, h, Wfi, Wfh, Wii, Wih, Wsi, Wsh, Woi, Woh,
                                       XH, WALL);
  prep_small<<<914, 256, 0, stream>>>(Wd1, Wd2, Wd3, bd2, bfi, bfh, bii, bih, bsi, bsh,
                                      boi, boh, WD1, WD2, WD3, BALL, BD2);

  // gates GEMM + fused LSTM -> h_out (f32) + H2 (f16)
  gemm_gates<<<dim3(32, 64), 256, 0, stream>>>(XH, WALL, BALL, c, h_out, H2);

  // fused decoder (3 GEMMs + softmax in one kernel)
  decoder_fused<<<512, 512, 0, stream>>>(H2, WD1, bd1, WD2, BD2, WD3, bd3, d_outp);
}